// Round 5
// baseline (322.265 us; speedup 1.0000x reference)
//
#include <hip/hip_runtime.h>
#include <hip/hip_bf16.h>

#define B_ 128
#define T_ 2048
#define H_ 128

typedef __attribute__((ext_vector_type(8))) short short8;
typedef __attribute__((ext_vector_type(4))) float f32x4;

__device__ __forceinline__ short8 pack8(const float4 x, const float4 y) {
    union { __hip_bfloat162 h2[4]; short8 s; } u;
    u.h2[0] = __float22bfloat162_rn(make_float2(x.x, x.y));
    u.h2[1] = __float22bfloat162_rn(make_float2(x.z, x.w));
    u.h2[2] = __float22bfloat162_rn(make_float2(y.x, y.y));
    u.h2[3] = __float22bfloat162_rn(make_float2(y.z, y.w));
    return u.s;
}
__device__ __forceinline__ float tanh_fast(float x) {
    x = fminf(fmaxf(x, -20.f), 20.f);
    float e = __expf(2.f * x);
    return (e - 1.f) / (e + 1.f);
}

// ---------------- Phase 1: energy[b,t] = W_a . tanh(W_h hp + W_d hd) + b_a ----
// GEMM rows = b*T+t (M=262144), N=128, K=256 (hp|hd). fp32 in, bf16 MFMA.
// B staged in LDS pre-swizzled to MFMA fragment order: ds_read_b128 is
// lane-contiguous (zero bank conflicts, immediate offsets). Each wave does
// 32 rows (2 m-sets) so every B fragment feeds 2 MFMAs.
__global__ __launch_bounds__(512) void energy_kernel(
    const float* __restrict__ Hp,
    const float* __restrict__ Hd,
    const float* __restrict__ Wh,
    const float* __restrict__ Wd,
    const float* __restrict__ Wa,
    const float* __restrict__ ba_p,
    float* __restrict__ energy,
    int ntiles)   // tiles of 256 rows
{
    // Bfrag[f = kt*8+nt][lane][j]: bf16, f<64, lane<64, j<8  -> 64 KB
    __shared__ unsigned short Bfrag[64 * 64 * 8];
    __shared__ float Was[H_];

    const int tid = threadIdx.x;

    // stage swizzled fragments: Bfrag[(f*64+l)*8+j] = W[nt*16+(l&15)][kt*32+((l>>4)<<3)+j]
    #pragma unroll
    for (int p = 0; p < 8; p++) {
        int fl = p * 512 + tid;      // (f,l) flat, 0..4095
        int f  = fl >> 6;
        int l  = fl & 63;
        int kt = f >> 3, nt = f & 7;
        int o   = nt * 16 + (l & 15);
        int col = kt * 32 + ((l >> 4) << 3);
        const float* src = (kt < 4) ? (Wh + o * H_ + col) : (Wd + o * H_ + (col - 128));
        float4 x0 = *(const float4*)src;
        float4 x1 = *(const float4*)(src + 4);
        *(short8*)&Bfrag[fl * 8] = pack8(x0, x1);
    }
    if (tid < H_) Was[tid] = Wa[tid];
    __syncthreads();

    const float ba = ba_p[0];

    const int wave = tid >> 6;     // 0..7
    const int lane = tid & 63;
    const int l15  = lane & 15;
    const int lq   = lane >> 4;    // 0..3

    for (int tile = blockIdx.x; tile < ntiles; tile += gridDim.x) {
        const int row0 = tile * 256 + wave * 32;
        const float* a0p = Hp + (size_t)(row0 + l15) * H_ + lq * 8;
        const float* a1p = a0p + 16 * H_;
        const float* a0d = Hd + (size_t)(row0 + l15) * H_ + lq * 8;
        const float* a1d = a0d + 16 * H_;

        f32x4 acc0[8], acc1[8];
        #pragma unroll
        for (int nt = 0; nt < 8; nt++) {
            acc0[nt] = (f32x4){0.f, 0.f, 0.f, 0.f};
            acc1[nt] = (f32x4){0.f, 0.f, 0.f, 0.f};
        }

        float4 p00 = *(const float4*)(a0p), p01 = *(const float4*)(a0p + 4);
        float4 p10 = *(const float4*)(a1p), p11 = *(const float4*)(a1p + 4);

        #pragma unroll 1
        for (int kt = 0; kt < 8; kt++) {
            float4 n00 = p00, n01 = p01, n10 = p10, n11 = p11;
            if (kt < 7) {          // wave-uniform branch; depth-1 prefetch
                int ktn = kt + 1;
                const float* q0 = (ktn < 4) ? (a0p + ktn * 32) : (a0d + (ktn - 4) * 32);
                const float* q1 = (ktn < 4) ? (a1p + ktn * 32) : (a1d + (ktn - 4) * 32);
                n00 = *(const float4*)q0; n01 = *(const float4*)(q0 + 4);
                n10 = *(const float4*)q1; n11 = *(const float4*)(q1 + 4);
            }
            short8 af0 = pack8(p00, p01);
            short8 af1 = pack8(p10, p11);
            const unsigned short* bp = &Bfrag[kt * 8 * 512 + lane * 8];
            #pragma unroll
            for (int nt = 0; nt < 8; nt++) {
                short8 bf = *(const short8*)(bp + nt * 512);   // lane-contig, imm offset
                acc0[nt] = __builtin_amdgcn_mfma_f32_16x16x32_bf16(af0, bf, acc0[nt], 0, 0, 0);
                acc1[nt] = __builtin_amdgcn_mfma_f32_16x16x32_bf16(af1, bf, acc1[nt], 0, 0, 0);
            }
            p00 = n00; p01 = n01; p10 = n10; p11 = n11;
        }

        float ep0[4] = {0.f, 0.f, 0.f, 0.f};
        float ep1[4] = {0.f, 0.f, 0.f, 0.f};
        #pragma unroll
        for (int nt = 0; nt < 8; nt++) {
            const float wa = Was[nt * 16 + l15];
            #pragma unroll
            for (int r = 0; r < 4; r++) {
                ep0[r] += tanh_fast(acc0[nt][r]) * wa;
                ep1[r] += tanh_fast(acc1[nt][r]) * wa;
            }
        }
        #pragma unroll
        for (int m = 1; m < 16; m <<= 1) {
            #pragma unroll
            for (int r = 0; r < 4; r++) {
                ep0[r] += __shfl_xor(ep0[r], m, 64);
                ep1[r] += __shfl_xor(ep1[r], m, 64);
            }
        }
        if (l15 == 0) {
            // C/D: col = lane&15, row(m) = lq*4 + r
            #pragma unroll
            for (int r = 0; r < 4; r++) {
                energy[row0 + lq * 4 + r]      = ep0[r] + ba;
                energy[row0 + 16 + lq * 4 + r] = ep1[r] + ba;
            }
        }
    }
}

// ---------------- Phase 2: fused softmax + partial context ----------------
// grid = B*16; block (b, sl) recomputes the softmax reductions (L2-resident,
// deterministic), writes its 128-t alpha slice, accumulates its ctx partial
// with 4 independent 16B loads in flight per lane.
__global__ __launch_bounds__(256) void softmax_ctx_kernel(
    const float* __restrict__ Hp,
    const float* __restrict__ accw,
    const float* __restrict__ beta_p,
    const float* __restrict__ energy,
    float* __restrict__ out_alpha,
    float* __restrict__ cpart)   // [B][16][H]
{
    __shared__ float al_s[T_];      // 8 KB
    __shared__ float red[8 * H_];   // 4 KB
    __shared__ float sred[8];

    const int sl   = blockIdx.x & 15;
    const int b    = blockIdx.x >> 4;
    const int tid  = threadIdx.x;
    const int lane = tid & 63;
    const int wid  = tid >> 6;   // 0..3

    const float beta_pos = log1pf(__expf(beta_p[0]));

    float av[8], ev[8];
    {
        const float* pa = accw + b * T_ + tid * 8;
        const float* pe = energy + b * T_ + tid * 8;
        float4 a0 = *(const float4*)pa, a1 = *(const float4*)(pa + 4);
        float4 e0 = *(const float4*)pe, e1 = *(const float4*)(pe + 4);
        av[0]=a0.x; av[1]=a0.y; av[2]=a0.z; av[3]=a0.w;
        av[4]=a1.x; av[5]=a1.y; av[6]=a1.z; av[7]=a1.w;
        ev[0]=e0.x; ev[1]=e0.y; ev[2]=e0.z; ev[3]=e0.w;
        ev[4]=e1.x; ev[5]=e1.y; ev[6]=e1.z; ev[7]=e1.w;
    }
    float amax = -1e30f;
    #pragma unroll
    for (int i = 0; i < 8; i++) amax = fmaxf(amax, av[i]);
    for (int m = 32; m >= 1; m >>= 1) amax = fmaxf(amax, __shfl_xor(amax, m, 64));
    if (lane == 0) sred[wid] = amax;
    __syncthreads();
    if (tid == 0)
        sred[4] = fmaxf(fmaxf(sred[0], sred[1]), fmaxf(sred[2], sred[3]));
    __syncthreads();
    const float invd = beta_pos / fmaxf(sred[4], 1e-6f);

    float sv[8], smax = -1e30f;
    #pragma unroll
    for (int i = 0; i < 8; i++) {
        sv[i] = ev[i] * (1.f + av[i] * invd);
        smax = fmaxf(smax, sv[i]);
    }
    for (int m = 32; m >= 1; m >>= 1) smax = fmaxf(smax, __shfl_xor(smax, m, 64));
    __syncthreads();
    if (lane == 0) sred[wid] = smax;
    __syncthreads();
    if (tid == 0)
        sred[5] = fmaxf(fmaxf(sred[0], sred[1]), fmaxf(sred[2], sred[3]));
    __syncthreads();
    const float smax_all = sred[5];

    float p[8], psum = 0.f;
    #pragma unroll
    for (int i = 0; i < 8; i++) { p[i] = __expf(sv[i] - smax_all); psum += p[i]; }
    for (int m = 32; m >= 1; m >>= 1) psum += __shfl_xor(psum, m, 64);
    __syncthreads();
    if (lane == 0) sred[wid] = psum;
    __syncthreads();
    if (tid == 0)
        sred[6] = sred[0] + sred[1] + sred[2] + sred[3];
    __syncthreads();
    const float invS = 1.f / sred[6];

    #pragma unroll
    for (int i = 0; i < 8; i++) al_s[tid * 8 + i] = p[i] * invS;
    __syncthreads();

    if (tid < 128)
        out_alpha[b * T_ + sl * 128 + tid] = al_s[sl * 128 + tid];

    // ---- context partial over t in [sl*128, sl*128+128) ----
    const int row = tid >> 5;      // 0..7
    const int c4  = tid & 31;      // float4 column within the 512B row

    const float* base = Hp + ((size_t)b * T_ + sl * 128) * H_ + c4 * 4;
    const float* al   = al_s + sl * 128;

    float4 s0 = {0,0,0,0}, s1 = {0,0,0,0}, s2 = {0,0,0,0}, s3 = {0,0,0,0};
    #pragma unroll
    for (int it = 0; it < 16; it += 4) {
        int t0 = (it + 0) * 8 + row, t1 = (it + 1) * 8 + row;
        int t2 = (it + 2) * 8 + row, t3 = (it + 3) * 8 + row;
        float a0 = al[t0], a1 = al[t1], a2 = al[t2], a3 = al[t3];
        float4 v0 = *(const float4*)(base + (size_t)t0 * H_);
        float4 v1 = *(const float4*)(base + (size_t)t1 * H_);
        float4 v2 = *(const float4*)(base + (size_t)t2 * H_);
        float4 v3 = *(const float4*)(base + (size_t)t3 * H_);
        s0.x += a0*v0.x; s0.y += a0*v0.y; s0.z += a0*v0.z; s0.w += a0*v0.w;
        s1.x += a1*v1.x; s1.y += a1*v1.y; s1.z += a1*v1.z; s1.w += a1*v1.w;
        s2.x += a2*v2.x; s2.y += a2*v2.y; s2.z += a2*v2.z; s2.w += a2*v2.w;
        s3.x += a3*v3.x; s3.y += a3*v3.y; s3.z += a3*v3.z; s3.w += a3*v3.w;
    }
    s0.x += s1.x + s2.x + s3.x;
    s0.y += s1.y + s2.y + s3.y;
    s0.z += s1.z + s2.z + s3.z;
    s0.w += s1.w + s2.w + s3.w;

    red[row * H_ + c4 * 4 + 0] = s0.x;
    red[row * H_ + c4 * 4 + 1] = s0.y;
    red[row * H_ + c4 * 4 + 2] = s0.z;
    red[row * H_ + c4 * 4 + 3] = s0.w;
    __syncthreads();
    if (tid < H_) {
        float s = 0.f;
        #pragma unroll
        for (int g = 0; g < 8; g++) s += red[g * H_ + tid];
        cpart[(b * 16 + sl) * H_ + tid] = s;
    }
}

__global__ __launch_bounds__(256) void ctx_reduce_kernel(
    const float* __restrict__ cpart, float* __restrict__ out_ctx)
{
    int i = blockIdx.x * 256 + threadIdx.x;   // i < B*H
    if (i < B_ * H_) {
        int b = i >> 7, h = i & 127;
        float s = 0.f;
        #pragma unroll
        for (int g = 0; g < 16; g++) s += cpart[(b * 16 + g) * H_ + h];
        out_ctx[i] = s;
    }
}

extern "C" void kernel_launch(void* const* d_in, const int* in_sizes, int n_in,
                              void* d_out, int out_size, void* d_ws, size_t ws_size,
                              hipStream_t stream) {
    const float* Hp   = (const float*)d_in[0];
    const float* Hd   = (const float*)d_in[1];
    const float* accw = (const float*)d_in[2];
    const float* Wh   = (const float*)d_in[3];
    const float* Wd   = (const float*)d_in[4];
    const float* Wa   = (const float*)d_in[5];
    const float* ba   = (const float*)d_in[6];
    const float* beta = (const float*)d_in[7];

    float* energy_ws = (float*)d_ws;                 // B*T fp32 = 1 MB
    float* cpart_ws  = energy_ws + B_ * T_;          // B*16*H fp32 = 1 MB

    float* out_ctx   = (float*)d_out;                // [B,H]
    float* out_alpha = out_ctx + B_ * H_;            // [B,T]

    const int ntiles = (B_ * T_) / 256;   // 1024 tiles of 256 rows
    energy_kernel<<<512, 512, 0, stream>>>(Hp, Hd, Wh, Wd, Wa, ba, energy_ws, ntiles);
    softmax_ctx_kernel<<<B_ * 16, 256, 0, stream>>>(Hp, accw, beta, energy_ws, out_alpha, cpart_ws);
    ctx_reduce_kernel<<<(B_ * H_ + 255) / 256, 256, 0, stream>>>(cpart_ws, out_ctx);
}